// Round 11
// baseline (175.053 us; speedup 1.0000x reference)
//
#include <hip/hip_runtime.h>
#include <math.h>

typedef float2 cplx;
typedef __attribute__((ext_vector_type(8))) short short8v;
typedef __attribute__((ext_vector_type(4))) short short4v;
typedef __attribute__((ext_vector_type(4))) float float4v;

#define IN_DIM 4000
#define NREPS 4

// 1/k! 0..15
#define C0f  1.0f
#define C1f  1.0f
#define C2f  0.5f
#define C3f  0.16666667f
#define C4f  0.041666668f
#define C5f  8.3333333e-3f
#define C6f  1.3888889e-3f
#define C7f  1.9841270e-4f
#define C8f  2.4801587e-5f
#define C9f  2.7557319e-6f
#define C10f 2.7557319e-7f
#define C11f 2.5052108e-8f
#define C12f 2.0876757e-9f
#define C13f 1.6059044e-10f
#define C14f 1.1470746e-11f
#define C15f 7.6471637e-13f

#define MFMA(A,B,C) __builtin_amdgcn_mfma_f32_16x16x32_bf16((A),(B),(C),0,0,0)

// ---------------------------------------------------------------------------
// Round-3 fused kernel VERBATIM (passed, rocprof dur 116us) with ONE launcher
// change: the 4-byte hipMemsetAsync flag-reset is replaced by a 1-block
// zero_flag KERNEL. Theory: the memset node lands on the SDMA engine; the
// SDMA->compute graph edge costs a cross-engine semaphore sync (~38us),
// which is exactly the bench-vs-rocprof gap every fused round paid
// (R3 153.8/116, R5 163/120, R9 177/137) and no two-kernel round paid
// (R0 155=79+76, R10 146.7=73.5+~70). Compute->compute edges are ~2-3us.
//
// Fused structure (R3-proven): grid 512, 512-thr blocks (8 waves), 67KB LDS
// -> 2 blocks/CU -> ALL blocks co-resident -> flag spin is deadlock-free.
// Blocks 0..3 first compute Up[b] = expm(-i H_w[b]) -> ws and release the
// device-scope flag; every block then computes its own sample's Ud expm and
// runs the 4-rep circuit. Makespan 2X+C.
//
// expm: 8 waves, 1x2 tiles/wave (mb=wv&3, nb=(wv>>2)*2). Frobenius prescale
// + Schatten-4 extra halvings (theta=3.4), degree-15 Taylor Horner, s
// squarings. LDS: S0/S1 = bf16 hi/lo planes {rh,rl,ih,il}, 32KB each.
// mm C = L*R; AM=2: storage holds conj(L); BM=1: storage rows are -R^T re.
// ---------------------------------------------------------------------------

__device__ __forceinline__ int idxSw(int a, int b) {
    return (a << 6) + ((((b >> 3) + a) & 7) << 3) + (b & 7);
}
__device__ __forceinline__ short f2bf(float f) {   // RNE to bf16
    unsigned u = __float_as_uint(f);
    return (short)((u + 0x7FFF + ((u >> 16) & 1)) >> 16);
}
__device__ __forceinline__ float bf2f(short s) {
    return __uint_as_float(((unsigned)(unsigned short)s) << 16);
}
__device__ __forceinline__ short8v neg8(short8v a) {
    int4 u; __builtin_memcpy(&u, &a, 16);
    u.x ^= 0x80008000; u.y ^= 0x80008000; u.z ^= 0x80008000; u.w ^= 0x80008000;
    short8v r; __builtin_memcpy(&r, &u, 16); return r;
}

// C = L*R. AM=2: storage holds conj(L). BM=1: storage rows are -R^T re.
template<int AM, int BM, int NDM, int NDN>
__device__ __forceinline__ void mm_mfma(const short* __restrict__ As,
                                        const short* __restrict__ Bs,
                                        int li, int q, int mb, int nb,
                                        float4v* __restrict__ accR,
                                        float4v* __restrict__ accI)
{
    #pragma unroll
    for (int ks = 0; ks < 2; ks++) {
        const int ch = ks * 4 + q;
        short8v arh[NDM], arl[NDM], cRh[NDM], cRl[NDM], cIh[NDM], cIl[NDM];
        #pragma unroll
        for (int dm = 0; dm < NDM; dm++) {
            int r = ((mb + dm) << 4) + li;
            int off = (r << 6) + (((ch + r) & 7) << 3);
            arh[dm] = *(const short8v*)(As + off);
            arl[dm] = *(const short8v*)(As + 4096 + off);
            short8v aih = *(const short8v*)(As + 8192 + off);
            short8v ail = *(const short8v*)(As + 12288 + off);
            short8v nih = neg8(aih), nil_ = neg8(ail);
            cRh[dm] = (AM == 2) ? aih : nih;
            cRl[dm] = (AM == 2) ? ail : nil_;
            cIh[dm] = (AM == 2) ? nih : aih;
            cIl[dm] = (AM == 2) ? nil_ : ail;
        }
        #pragma unroll
        for (int dn = 0; dn < NDN; dn++) {
            int n = ((nb + dn) << 4) + li;
            int off = (n << 6) + (((ch + n) & 7) << 3);
            short8v brh = *(const short8v*)(Bs + off);
            short8v brl = *(const short8v*)(Bs + 4096 + off);
            short8v bih = *(const short8v*)(Bs + 8192 + off);
            short8v bil = *(const short8v*)(Bs + 12288 + off);
            if (BM == 1) { brh = neg8(brh); brl = neg8(brl); }
            __builtin_amdgcn_s_setprio(1);
            #pragma unroll
            for (int dm = 0; dm < NDM; dm++) {
                int ti = dm * NDN + dn;
                accR[ti] = MFMA(arh[dm], brh, accR[ti]);
                accR[ti] = MFMA(arh[dm], brl, accR[ti]);
                accR[ti] = MFMA(arl[dm], brh, accR[ti]);
                accR[ti] = MFMA(cRh[dm], bih, accR[ti]);
                accR[ti] = MFMA(cRh[dm], bil, accR[ti]);
                accR[ti] = MFMA(cRl[dm], bih, accR[ti]);
                accI[ti] = MFMA(arh[dm], bih, accI[ti]);
                accI[ti] = MFMA(arh[dm], bil, accI[ti]);
                accI[ti] = MFMA(arl[dm], bih, accI[ti]);
                accI[ti] = MFMA(cIh[dm], brh, accI[ti]);
                accI[ti] = MFMA(cIh[dm], brl, accI[ti]);
                accI[ti] = MFMA(cIl[dm], brh, accI[ti]);
            }
            __builtin_amdgcn_s_setprio(0);
        }
    }
}

template<int NDM, int NDN>
__device__ __forceinline__ void write_row(short* __restrict__ S, int li, int q,
                                          int mb, int nb,
                                          const float4v* cre, const float4v* cim)
{
    #pragma unroll
    for (int dm = 0; dm < NDM; dm++)
    #pragma unroll
    for (int dn = 0; dn < NDN; dn++) {
        int ti = dm * NDN + dn;
        int c = ((nb + dn) << 4) + li;
        #pragma unroll
        for (int reg = 0; reg < 4; reg++) {
            int r = ((mb + dm) << 4) + q * 4 + reg;
            int off = idxSw(r, c);
            float vr = cre[ti][reg], vi = cim[ti][reg];
            short rh = f2bf(vr), rl = f2bf(vr - bf2f(rh));
            short ih = f2bf(vi), il = f2bf(vi - bf2f(ih));
            S[off] = rh; S[4096 + off] = rl; S[8192 + off] = ih; S[12288 + off] = il;
        }
    }
}

template<int NDM, int NDN>
__device__ __forceinline__ void write_rowT(short* __restrict__ S, int li, int q,
                                           int mb, int nb,
                                           const float4v* cre, const float4v* cim)
{
    #pragma unroll
    for (int dm = 0; dm < NDM; dm++)
    #pragma unroll
    for (int dn = 0; dn < NDN; dn++) {
        int ti = dm * NDN + dn;
        int c = ((nb + dn) << 4) + li;
        int k0 = ((mb + dm) << 4) + q * 4;
        int off = idxSw(c, k0);
        short4v rh, rl, ih, il;
        #pragma unroll
        for (int reg = 0; reg < 4; reg++) {
            float vr = cre[ti][reg], vi = cim[ti][reg];
            short h1 = f2bf(vr); rh[reg] = h1; rl[reg] = f2bf(vr - bf2f(h1));
            short h2 = f2bf(vi); ih[reg] = h2; il[reg] = f2bf(vi - bf2f(h2));
        }
        *(short4v*)(S + off) = rh;
        *(short4v*)(S + 4096 + off) = rl;
        *(short4v*)(S + 8192 + off) = ih;
        *(short4v*)(S + 12288 + off) = il;
    }
}

template<int NDM, int NDN>
__device__ __forceinline__ void gather_tile(const short* __restrict__ S, int li, int q,
                                            int mb, int nb, float4v* bre, float4v* bim)
{
    #pragma unroll
    for (int dm = 0; dm < NDM; dm++)
    #pragma unroll
    for (int dn = 0; dn < NDN; dn++) {
        int ti = dm * NDN + dn;
        int c = ((nb + dn) << 4) + li;
        #pragma unroll
        for (int reg = 0; reg < 4; reg++) {
            int r = ((mb + dm) << 4) + q * 4 + reg;
            int off = idxSw(r, c);
            bre[ti][reg] = bf2f(S[off]) + bf2f(S[4096 + off]);
            bim[ti][reg] = bf2f(S[8192 + off]) + bf2f(S[12288 + off]);
        }
    }
}

template<int NDM, int NDN>
__device__ __forceinline__ void adddiag(float4v* u, float cI, int li, int q, int mb, int nb)
{
    #pragma unroll
    for (int dm = 0; dm < NDM; dm++)
    #pragma unroll
    for (int dn = 0; dn < NDN; dn++) {
        if (mb + dm == nb + dn) {
            #pragma unroll
            for (int e = 0; e < 4; e++)
                if (li == q * 4 + e) u[dm * NDN + dn][e] += cI;
        }
    }
}

// C-layout tiles -> plain-swizzled fp32 matrix (LDS or global)
template<int NDM, int NDN>
__device__ __forceinline__ void store_tiles(cplx* __restrict__ dst, int li, int q,
                                            int mb, int nb,
                                            const float4v* ure, const float4v* uim)
{
    #pragma unroll
    for (int dm = 0; dm < NDM; dm++)
    #pragma unroll
    for (int dn = 0; dn < NDN; dn++) {
        int ti = dm * NDN + dn;
        int c = ((nb + dn) << 4) + li;
        int cs = c ^ (((c >> 4) & 1) << 1);
        #pragma unroll
        for (int reg = 0; reg < 4; reg++) {
            int r = ((mb + dm) << 4) + q * 4 + reg;
            dst[(r << 6) + cs] = make_float2(ure[ti][reg], uim[ti][reg]);
        }
    }
}

__device__ __forceinline__ cplx pauli_phase(float v, int xm, int zm) {
    int ny = __popc(xm & zm) & 3;
    if (ny == 0) return make_float2(v, 0.f);
    if (ny == 1) return make_float2(0.f, -v);
    if (ny == 2) return make_float2(-v, 0.f);
    return make_float2(0.f, v);
}

// Full expm at WPB=8 (8 waves, 1x2 tiles/wave: mb=wv&3, nb=(wv>>2)*2).
// Leaves U = exp(-iH) in C-layout regs. All LDS reads fenced on return.
__device__ __forceinline__ void expm_core8(char* __restrict__ LDS,
                                           const float* __restrict__ src, bool isW,
                                           int t, float4v* ure, float4v* uim)
{
    constexpr int NDM = 1, NDN = 2, NT = 2;
    short* S0 = (short*)LDS;
    short* S1 = (short*)(LDS + 32768);
    cplx*  W  = (cplx*)(LDS + 32768);
    float* red = (float*)(LDS + 65536);
    const int lane = t & 63, wv = t >> 6;
    const int li = lane & 15, q = lane >> 4;
    const int mb = wv & 3, nb = (wv >> 2) << 1;

    // ---- load coefficients -> W[m=xmask][z=zmask]; wave-reduced sumsq ----
    float sumsq = 0.f;
    #pragma unroll
    for (int n = 0; n < 8; n++) {
        int p = t + 512 * n;
        int xm = 0, zm = 0;
        #pragma unroll
        for (int k = 0; k < 6; k++) {
            int d = (p >> (2 * k)) & 3;
            int hi = d >> 1, lo = d & 1;
            zm |= hi << k; xm |= (hi ^ lo) << k;
        }
        float v = isW ? ((p == 0) ? 0.f : src[p - 1])
                      : ((p < IN_DIM) ? src[p] : 0.f);
        sumsq += v * v;
        W[(xm << 6) + zm] = pauli_phase(v, xm, zm);
    }
    #pragma unroll
    for (int d = 32; d >= 1; d >>= 1) sumsq += __shfl_xor(sumsq, d, 64);
    if (lane == 0) red[wv] = sumsq;
    __syncthreads();

    // ---- Frobenius prescale: ||B||_2 <= fro/2^s1 in (4,8] ----
    float rs = 0.f;
    #pragma unroll
    for (int i2 = 0; i2 < 8; i2++) rs += red[i2];
    float fro = sqrtf(64.f * rs);
    int s1 = 0; { float nn = fro; while (nn > 8.f && s1 < 24) { nn *= 0.5f; s1++; } }
    float sc1 = exp2f((float)(-s1));

    // ---- in-register WHT: lane = z-index, 8 rows per wave ----
    cplx hv[8];
    #pragma unroll
    for (int rr = 0; rr < 8; rr++) hv[rr] = W[((wv * 8 + rr) << 6) + lane];
    #pragma unroll
    for (int d = 1; d < 64; d <<= 1) {
        float sg = (lane & d) ? -1.f : 1.f;
        #pragma unroll
        for (int rr = 0; rr < 8; rr++) {
            float px = __shfl_xor(hv[rr].x, d, 64);
            float py = __shfl_xor(hv[rr].y, d, 64);
            hv[rr].x = fmaf(sg, hv[rr].x, px);
            hv[rr].y = fmaf(sg, hv[rr].y, py);
        }
    }
    // ---- scatter B[l][l^m] = -i*h_m(l)*sc1 -> S0 planes ----
    #pragma unroll
    for (int rr = 0; rr < 8; rr++) {
        int m = wv * 8 + rr;
        int c = lane ^ m;
        float vr = hv[rr].y * sc1, vi = -hv[rr].x * sc1;
        short rh = f2bf(vr), rl = f2bf(vr - bf2f(rh));
        short ih = f2bf(vi), il = f2bf(vi - bf2f(ih));
        int off = idxSw(lane, c);
        S0[off] = rh; S0[4096 + off] = rl; S0[8192 + off] = ih; S0[12288 + off] = il;
    }
    __syncthreads();

    const float4v z4 = {0.f, 0.f, 0.f, 0.f};
    float4v accR[NT], accI[NT];
    #define ZERO_ACC _Pragma("unroll") for (int i2 = 0; i2 < NT; i2++) { accR[i2]=z4; accI[i2]=z4; }

    // ---- mm1: B2 = B*B ----
    ZERO_ACC
    mm_mfma<0, 1, NDM, NDN>(S0, S0, li, q, mb, nb, accR, accI);
    float ss = 0.f;
    #pragma unroll
    for (int ti = 0; ti < NT; ti++)
        #pragma unroll
        for (int e = 0; e < 4; e++)
            ss += accR[ti][e]*accR[ti][e] + accI[ti][e]*accI[ti][e];
    #pragma unroll
    for (int d = 32; d >= 1; d >>= 1) ss += __shfl_xor(ss, d, 64);
    if (lane == 0) red[8 + wv] = ss;
    __syncthreads();

    // ---- Schatten-4 bound -> extra halvings; theta = 3.4 ----
    rs = 0.f;
    #pragma unroll
    for (int i2 = 0; i2 < 8; i2++) rs += red[8 + i2];
    float bound = sqrtf(sqrtf(rs));
    int ds = 0; { float nn = bound; while (nn > 3.4f && ds < 12) { nn *= 0.5f; ds++; } }
    const int s = s1 + ds;
    float dsc = exp2f((float)(-ds)), dsc2 = dsc * dsc;

    // ---- B tile (C-layout) for Horner combos ----
    float4v bre[NT], bim[NT];
    gather_tile<NDM, NDN>(S0, li, q, mb, nb, bre, bim);

    // ---- S1 <- A2^T = (dsc^2*B2)^T (= conj(A2)) ----
    #pragma unroll
    for (int ti = 0; ti < NT; ti++) { ure[ti] = accR[ti] * dsc2; uim[ti] = accI[ti] * dsc2; }
    write_rowT<NDM, NDN>(S1, li, q, mb, nb, ure, uim);
    __syncthreads();

    // ---- S0 <- V7^T, V7 = c14 I + c15 A ----
    {
        float ca = C15f * dsc;
        #pragma unroll
        for (int ti = 0; ti < NT; ti++) { ure[ti] = ca * bre[ti]; uim[ti] = ca * bim[ti]; }
        adddiag<NDM, NDN>(ure, C14f, li, q, mb, nb);
        write_rowT<NDM, NDN>(S0, li, q, mb, nb, ure, uim);
    }
    __syncthreads();

    // ---- Horner: V_j = cI_j I + cA_j A + A2*V_{j+1}, j = 6..0 ----
    const float cIc[7] = { C0f, C2f, C4f, C6f, C8f, C10f, C12f };
    const float cAc[7] = { C1f, C3f, C5f, C7f, C9f, C11f, C13f };
    for (int j = 6; j >= 0; j--) {
        ZERO_ACC
        mm_mfma<2, 0, NDM, NDN>(S1, S0, li, q, mb, nb, accR, accI);
        __syncthreads();
        float ca = cAc[j] * dsc, cI = cIc[j];
        #pragma unroll
        for (int ti = 0; ti < NT; ti++) {
            ure[ti] = accR[ti] + ca * bre[ti];
            uim[ti] = accI[ti] + ca * bim[ti];
        }
        adddiag<NDM, NDN>(ure, cI, li, q, mb, nb);
        write_rowT<NDM, NDN>(S0, li, q, mb, nb, ure, uim);
        __syncthreads();
    }

    // ---- s squarings: U <- U*U (A-side U in S1, B-side U^T in S0) ----
    for (int sq = 0; sq < s; sq++) {
        write_row<NDM, NDN>(S1, li, q, mb, nb, ure, uim);
        if (sq > 0) write_rowT<NDM, NDN>(S0, li, q, mb, nb, ure, uim);
        __syncthreads();
        ZERO_ACC
        mm_mfma<0, 0, NDM, NDN>(S1, S0, li, q, mb, nb, accR, accI);
        __syncthreads();
        #pragma unroll
        for (int ti = 0; ti < NT; ti++) { ure[ti] = accR[ti]; uim[ti] = accI[ti]; }
    }
    #undef ZERO_ACC
}

// 8-wave matvec: wave wv computes rows 8wv..8wv+7, k split 8-way by lane>>3,
// in-register shuffle reduce. M plain-swizzled fp32 (cs = c ^ ((c>>4)&1)<<1).
__device__ __forceinline__ cplx matvec_wave8(const cplx* __restrict__ M,
                                             const cplx* __restrict__ pin,
                                             int lane, int wv)
{
    const int ri = lane & 7;
    const int rr = (wv << 3) + ri;
    const int kc = lane >> 3;            // k-chunk 0..7, 8 cplx each
    const int ch = (kc + ri) & 7;        // rotate to spread LDS banks
    const int b  = (ch >> 1) & 1;        // swizzle decode (bit4 of c = bit1 of ch)
    const float4* Mr = (const float4*)(M + (rr << 6)) + (ch << 2);
    float4 m0 = Mr[0 ^ b], m1 = Mr[1 ^ b], m2 = Mr[2 ^ b], m3 = Mr[3 ^ b];
    const cplx* p = pin + (ch << 3);
    cplx p0 = p[0], p1 = p[1], p2 = p[2], p3 = p[3];
    cplx p4 = p[4], p5 = p[5], p6 = p[6], p7 = p[7];
    float ax = 0.f, ay = 0.f;
    ax = fmaf(m0.x, p0.x, fmaf(-m0.y, p0.y, ax));
    ay = fmaf(m0.x, p0.y, fmaf( m0.y, p0.x, ay));
    ax = fmaf(m0.z, p1.x, fmaf(-m0.w, p1.y, ax));
    ay = fmaf(m0.z, p1.y, fmaf( m0.w, p1.x, ay));
    ax = fmaf(m1.x, p2.x, fmaf(-m1.y, p2.y, ax));
    ay = fmaf(m1.x, p2.y, fmaf( m1.y, p2.x, ay));
    ax = fmaf(m1.z, p3.x, fmaf(-m1.w, p3.y, ax));
    ay = fmaf(m1.z, p3.y, fmaf( m1.w, p3.x, ay));
    ax = fmaf(m2.x, p4.x, fmaf(-m2.y, p4.y, ax));
    ay = fmaf(m2.x, p4.y, fmaf( m2.y, p4.x, ay));
    ax = fmaf(m2.z, p5.x, fmaf(-m2.w, p5.y, ax));
    ay = fmaf(m2.z, p5.y, fmaf( m2.w, p5.x, ay));
    ax = fmaf(m3.x, p6.x, fmaf(-m3.y, p6.y, ax));
    ay = fmaf(m3.x, p6.y, fmaf( m3.y, p6.x, ay));
    ax = fmaf(m3.z, p7.x, fmaf(-m3.w, p7.y, ax));
    ay = fmaf(m3.z, p7.y, fmaf( m3.w, p7.x, ay));
    ax += __shfl_xor(ax, 8, 64);  ay += __shfl_xor(ay, 8, 64);
    ax += __shfl_xor(ax, 16, 64); ay += __shfl_xor(ay, 16, 64);
    ax += __shfl_xor(ax, 32, 64); ay += __shfl_xor(ay, 32, 64);
    return make_float2(ax, ay);
}

// ===== flag reset on the COMPUTE engine (replaces SDMA memset node) =====
__global__ void zero_flag(int* __restrict__ flag)
{
    if (threadIdx.x == 0) *flag = 0;
}

// ===== fused kernel: grid = B = 512; blocks 0..3 also produce Up[b] =====
__global__ __launch_bounds__(512) void circuit_kernel(const float* __restrict__ x,
                                                      const float* __restrict__ w,
                                                      const float* __restrict__ bias,
                                                      cplx* __restrict__ ws,
                                                      int* __restrict__ flag,
                                                      float* __restrict__ out)
{
    __shared__ float4 LDSf4[4168];          // 66688 B -> 2 blocks/CU
    char* LDS = (char*)LDSf4;
    const int t = threadIdx.x, b = blockIdx.x;
    const int lane = t & 63, wv = t >> 6, li = lane & 15, q = lane >> 4;
    const int mb = wv & 3, nb = (wv >> 2) << 1;
    float4v ure[2], uim[2];

    // duty loop keeps ONE inlined expm_core8 instance (register hygiene):
    // producers (b<4) run duty 0 (Up[b] -> ws) then duty 1 (own sample).
    for (int duty = (b < NREPS) ? 0 : 1; duty < 2; duty++) {
        const bool isW = (duty == 0);
        const float* src = isW ? (w + (size_t)b * 4095) : (x + (size_t)b * IN_DIM);
        expm_core8(LDS, src, isW, t, ure, uim);
        if (isW) {
            store_tiles<1, 2>(ws + ((size_t)b << 12), li, q, mb, nb, ure, uim);
            __syncthreads();                 // barrier drains vmcnt -> stores done
            if (t == 0)
                __hip_atomic_fetch_add(flag, 1, __ATOMIC_RELEASE, __HIP_MEMORY_SCOPE_AGENT);
        }
    }

    cplx* Ud   = (cplx*)(LDS + 32768);      // overwrites S1 planes (fenced)
    cplx* UpS  = (cplx*)LDS;                // overwrites S0 planes
    cplx* psiA = (cplx*)(LDS + 65664);
    cplx* psiB = (cplx*)(LDS + 66176);

    store_tiles<1, 2>(Ud, li, q, mb, nb, ure, uim);
    if (t < 64) psiA[t] = make_float2(t == 0 ? 1.f : 0.f, 0.f);
    if (t == 0) {                            // Up ready? (producers done ~ same time)
        while (__hip_atomic_load(flag, __ATOMIC_ACQUIRE, __HIP_MEMORY_SCOPE_AGENT) < NREPS)
            __builtin_amdgcn_s_sleep(8);
    }
    __syncthreads();                         // fences Ud, psiA, flag acquire

    const int rowi = (wv << 3) + (lane & 7);
    for (int r = 0; r < NREPS; r++) {
        {   // stage Up[r] into S0 region (read after the mid barrier)
            const float4* srcv = (const float4*)(ws + ((size_t)r << 12));
            float4* dstY = (float4*)UpS;
            #pragma unroll
            for (int n = 0; n < 4; n++) dstY[n * 512 + t] = srcv[n * 512 + t];
        }
        cplx v1 = matvec_wave8(Ud, psiA, lane, wv);
        if (lane < 8) psiB[rowi] = v1;
        __syncthreads();                    // fences stage + psiB
        cplx v2 = matvec_wave8(UpS, psiB, lane, wv);
        if (lane < 8) psiA[rowi] = v2;
        __syncthreads();                    // fences psiA + UpS reuse
    }
    if (t < 64) {
        cplx pv = psiA[t];
        out[(b << 6) + t] = fmaf(pv.x, pv.x, fmaf(pv.y, pv.y, bias[t]));
    }
}

extern "C" void kernel_launch(void* const* d_in, const int* in_sizes, int n_in,
                              void* d_out, int out_size, void* d_ws, size_t ws_size,
                              hipStream_t stream)
{
    const float* x    = (const float*)d_in[0];
    const float* w    = (const float*)d_in[1];
    const float* bias = (const float*)d_in[2];
    float* out = (float*)d_out;
    cplx* ws   = (cplx*)d_ws;                         // 4 * 32 KB Up matrices
    int* flag  = (int*)((char*)d_ws + (NREPS << 15)); // flag at +131072

    int B = in_sizes[0] / IN_DIM;           // 512

    // compute-engine flag reset: avoids the SDMA memset node and its
    // cross-engine graph-edge sync (~38us, the fused rounds' bench overhead)
    hipLaunchKernelGGL(zero_flag, dim3(1), dim3(64), 0, stream, flag);
    hipLaunchKernelGGL(circuit_kernel, dim3(B), dim3(512), 0, stream,
                       x, w, bias, ws, flag, out);
}

// Round 12
// 146.022 us; speedup vs baseline: 1.1988x; 1.1988x over previous
//
#include <hip/hip_runtime.h>
#include <math.h>

typedef float2 cplx;
typedef __attribute__((ext_vector_type(8))) short short8v;
typedef __attribute__((ext_vector_type(4))) short short4v;
typedef __attribute__((ext_vector_type(4))) float float4v;

#define IN_DIM 4000
#define NREPS 4

// 1/k! 0..15
#define C0f  1.0f
#define C1f  1.0f
#define C2f  0.5f
#define C3f  0.16666667f
#define C4f  0.041666668f
#define C5f  8.3333333e-3f
#define C6f  1.3888889e-3f
#define C7f  1.9841270e-4f
#define C8f  2.4801587e-5f
#define C9f  2.7557319e-6f
#define C10f 2.7557319e-7f
#define C11f 2.5052108e-8f
#define C12f 2.0876757e-9f
#define C13f 1.6059044e-10f
#define C14f 1.1470746e-11f
#define C15f 7.6471637e-13f

#define MFMA(A,B,C) __builtin_amdgcn_mfma_f32_16x16x32_bf16((A),(B),(C),0,0,0)

// ---------------------------------------------------------------------------
// R10 (best, 146.7us) with ONE contained change: up_kernel's 16-wave core
// uses the 17-phase schedule (1-barrier squarings via 4-quad pair ping-pong
// + j=0 writes U row->P0 AND U^T->P3 in its own phase). 23 -> 17 barriers.
// R11 refuted the SDMA-gap theory (zero_flag kernel left the 46us gap
// unchanged) -> the ~35-45us is constant harness overhead in EVERY round;
// only kernel-sum matters. Kernel-sum = up(38) + circuit(73.5); this round
// targets up: 38 -> ~29.
//
// Squaring pairs: sq even reads (P0=U, P3=U^T) writes (P1,P2); sq odd reads
// (P1,P2) writes (P0,P3). Every write target was last read BEFORE the
// previous barrier (one barrier between all producer/consumer pairs).
// Risk containment: only up_kernel (4 blocks, W matrices); circuit_kernel
// and launcher are R10-verbatim.
// ---------------------------------------------------------------------------

__device__ __forceinline__ int idxSw(int a, int b) {
    return (a << 6) + ((((b >> 3) + a) & 7) << 3) + (b & 7);
}
__device__ __forceinline__ short f2bf(float f) {   // RNE to bf16
    unsigned u = __float_as_uint(f);
    return (short)((u + 0x7FFF + ((u >> 16) & 1)) >> 16);
}
__device__ __forceinline__ float bf2f(short s) {
    return __uint_as_float(((unsigned)(unsigned short)s) << 16);
}
__device__ __forceinline__ short8v neg8(short8v a) {
    int4 u; __builtin_memcpy(&u, &a, 16);
    u.x ^= 0x80008000; u.y ^= 0x80008000; u.z ^= 0x80008000; u.w ^= 0x80008000;
    short8v r; __builtin_memcpy(&r, &u, 16); return r;
}

__device__ __forceinline__ cplx pauli_phase(float v, int xm, int zm) {
    int ny = __popc(xm & zm) & 3;
    if (ny == 0) return make_float2(v, 0.f);
    if (ny == 1) return make_float2(0.f, -v);
    if (ny == 2) return make_float2(-v, 0.f);
    return make_float2(0.f, v);
}

// ======================= 8-wave (R3-verbatim) helpers =======================

template<int AM, int BM, int NDM, int NDN>
__device__ __forceinline__ void mm_mfma(const short* __restrict__ As,
                                        const short* __restrict__ Bs,
                                        int li, int q, int mb, int nb,
                                        float4v* __restrict__ accR,
                                        float4v* __restrict__ accI)
{
    #pragma unroll
    for (int ks = 0; ks < 2; ks++) {
        const int ch = ks * 4 + q;
        short8v arh[NDM], arl[NDM], cRh[NDM], cRl[NDM], cIh[NDM], cIl[NDM];
        #pragma unroll
        for (int dm = 0; dm < NDM; dm++) {
            int r = ((mb + dm) << 4) + li;
            int off = (r << 6) + (((ch + r) & 7) << 3);
            arh[dm] = *(const short8v*)(As + off);
            arl[dm] = *(const short8v*)(As + 4096 + off);
            short8v aih = *(const short8v*)(As + 8192 + off);
            short8v ail = *(const short8v*)(As + 12288 + off);
            short8v nih = neg8(aih), nil_ = neg8(ail);
            cRh[dm] = (AM == 2) ? aih : nih;
            cRl[dm] = (AM == 2) ? ail : nil_;
            cIh[dm] = (AM == 2) ? nih : aih;
            cIl[dm] = (AM == 2) ? nil_ : ail;
        }
        #pragma unroll
        for (int dn = 0; dn < NDN; dn++) {
            int n = ((nb + dn) << 4) + li;
            int off = (n << 6) + (((ch + n) & 7) << 3);
            short8v brh = *(const short8v*)(Bs + off);
            short8v brl = *(const short8v*)(Bs + 4096 + off);
            short8v bih = *(const short8v*)(Bs + 8192 + off);
            short8v bil = *(const short8v*)(Bs + 12288 + off);
            if (BM == 1) { brh = neg8(brh); brl = neg8(brl); }
            __builtin_amdgcn_s_setprio(1);
            #pragma unroll
            for (int dm = 0; dm < NDM; dm++) {
                int ti = dm * NDN + dn;
                accR[ti] = MFMA(arh[dm], brh, accR[ti]);
                accR[ti] = MFMA(arh[dm], brl, accR[ti]);
                accR[ti] = MFMA(arl[dm], brh, accR[ti]);
                accR[ti] = MFMA(cRh[dm], bih, accR[ti]);
                accR[ti] = MFMA(cRh[dm], bil, accR[ti]);
                accR[ti] = MFMA(cRl[dm], bih, accR[ti]);
                accI[ti] = MFMA(arh[dm], bih, accI[ti]);
                accI[ti] = MFMA(arh[dm], bil, accI[ti]);
                accI[ti] = MFMA(arl[dm], bih, accI[ti]);
                accI[ti] = MFMA(cIh[dm], brh, accI[ti]);
                accI[ti] = MFMA(cIh[dm], brl, accI[ti]);
                accI[ti] = MFMA(cIl[dm], brh, accI[ti]);
            }
            __builtin_amdgcn_s_setprio(0);
        }
    }
}

template<int NDM, int NDN>
__device__ __forceinline__ void write_row(short* __restrict__ S, int li, int q,
                                          int mb, int nb,
                                          const float4v* cre, const float4v* cim)
{
    #pragma unroll
    for (int dm = 0; dm < NDM; dm++)
    #pragma unroll
    for (int dn = 0; dn < NDN; dn++) {
        int ti = dm * NDN + dn;
        int c = ((nb + dn) << 4) + li;
        #pragma unroll
        for (int reg = 0; reg < 4; reg++) {
            int r = ((mb + dm) << 4) + q * 4 + reg;
            int off = idxSw(r, c);
            float vr = cre[ti][reg], vi = cim[ti][reg];
            short rh = f2bf(vr), rl = f2bf(vr - bf2f(rh));
            short ih = f2bf(vi), il = f2bf(vi - bf2f(ih));
            S[off] = rh; S[4096 + off] = rl; S[8192 + off] = ih; S[12288 + off] = il;
        }
    }
}

template<int NDM, int NDN>
__device__ __forceinline__ void write_rowT(short* __restrict__ S, int li, int q,
                                           int mb, int nb,
                                           const float4v* cre, const float4v* cim)
{
    #pragma unroll
    for (int dm = 0; dm < NDM; dm++)
    #pragma unroll
    for (int dn = 0; dn < NDN; dn++) {
        int ti = dm * NDN + dn;
        int c = ((nb + dn) << 4) + li;
        int k0 = ((mb + dm) << 4) + q * 4;
        int off = idxSw(c, k0);
        short4v rh, rl, ih, il;
        #pragma unroll
        for (int reg = 0; reg < 4; reg++) {
            float vr = cre[ti][reg], vi = cim[ti][reg];
            short h1 = f2bf(vr); rh[reg] = h1; rl[reg] = f2bf(vr - bf2f(h1));
            short h2 = f2bf(vi); ih[reg] = h2; il[reg] = f2bf(vi - bf2f(h2));
        }
        *(short4v*)(S + off) = rh;
        *(short4v*)(S + 4096 + off) = rl;
        *(short4v*)(S + 8192 + off) = ih;
        *(short4v*)(S + 12288 + off) = il;
    }
}

template<int NDM, int NDN>
__device__ __forceinline__ void gather_tile(const short* __restrict__ S, int li, int q,
                                            int mb, int nb, float4v* bre, float4v* bim)
{
    #pragma unroll
    for (int dm = 0; dm < NDM; dm++)
    #pragma unroll
    for (int dn = 0; dn < NDN; dn++) {
        int ti = dm * NDN + dn;
        int c = ((nb + dn) << 4) + li;
        #pragma unroll
        for (int reg = 0; reg < 4; reg++) {
            int r = ((mb + dm) << 4) + q * 4 + reg;
            int off = idxSw(r, c);
            bre[ti][reg] = bf2f(S[off]) + bf2f(S[4096 + off]);
            bim[ti][reg] = bf2f(S[8192 + off]) + bf2f(S[12288 + off]);
        }
    }
}

template<int NDM, int NDN>
__device__ __forceinline__ void adddiag(float4v* u, float cI, int li, int q, int mb, int nb)
{
    #pragma unroll
    for (int dm = 0; dm < NDM; dm++)
    #pragma unroll
    for (int dn = 0; dn < NDN; dn++) {
        if (mb + dm == nb + dn) {
            #pragma unroll
            for (int e = 0; e < 4; e++)
                if (li == q * 4 + e) u[dm * NDN + dn][e] += cI;
        }
    }
}

template<int NDM, int NDN>
__device__ __forceinline__ void store_tiles(cplx* __restrict__ dst, int li, int q,
                                            int mb, int nb,
                                            const float4v* ure, const float4v* uim)
{
    #pragma unroll
    for (int dm = 0; dm < NDM; dm++)
    #pragma unroll
    for (int dn = 0; dn < NDN; dn++) {
        int ti = dm * NDN + dn;
        int c = ((nb + dn) << 4) + li;
        int cs = c ^ (((c >> 4) & 1) << 1);
        #pragma unroll
        for (int reg = 0; reg < 4; reg++) {
            int r = ((mb + dm) << 4) + q * 4 + reg;
            dst[(r << 6) + cs] = make_float2(ure[ti][reg], uim[ti][reg]);
        }
    }
}

// ===== expm core, 8 waves (R3-verbatim; 2-quad S0/S1 layout, 67KB LDS) =====
__device__ __forceinline__ void expm_core8(char* __restrict__ LDS,
                                           const float* __restrict__ src, bool isW,
                                           int t, float4v* ure, float4v* uim)
{
    constexpr int NDM = 1, NDN = 2, NT = 2;
    short* S0 = (short*)LDS;
    short* S1 = (short*)(LDS + 32768);
    cplx*  W  = (cplx*)(LDS + 32768);
    float* red = (float*)(LDS + 65536);
    const int lane = t & 63, wv = t >> 6;
    const int li = lane & 15, q = lane >> 4;
    const int mb = wv & 3, nb = (wv >> 2) << 1;

    float sumsq = 0.f;
    #pragma unroll
    for (int n = 0; n < 8; n++) {
        int p = t + 512 * n;
        int xm = 0, zm = 0;
        #pragma unroll
        for (int k = 0; k < 6; k++) {
            int d = (p >> (2 * k)) & 3;
            int hi = d >> 1, lo = d & 1;
            zm |= hi << k; xm |= (hi ^ lo) << k;
        }
        float v = isW ? ((p == 0) ? 0.f : src[p - 1])
                      : ((p < IN_DIM) ? src[p] : 0.f);
        sumsq += v * v;
        W[(xm << 6) + zm] = pauli_phase(v, xm, zm);
    }
    #pragma unroll
    for (int d = 32; d >= 1; d >>= 1) sumsq += __shfl_xor(sumsq, d, 64);
    if (lane == 0) red[wv] = sumsq;
    __syncthreads();

    float rs = 0.f;
    #pragma unroll
    for (int i2 = 0; i2 < 8; i2++) rs += red[i2];
    float fro = sqrtf(64.f * rs);
    int s1 = 0; { float nn = fro; while (nn > 8.f && s1 < 24) { nn *= 0.5f; s1++; } }
    float sc1 = exp2f((float)(-s1));

    cplx hv[8];
    #pragma unroll
    for (int rr = 0; rr < 8; rr++) hv[rr] = W[((wv * 8 + rr) << 6) + lane];
    #pragma unroll
    for (int d = 1; d < 64; d <<= 1) {
        float sg = (lane & d) ? -1.f : 1.f;
        #pragma unroll
        for (int rr = 0; rr < 8; rr++) {
            float px = __shfl_xor(hv[rr].x, d, 64);
            float py = __shfl_xor(hv[rr].y, d, 64);
            hv[rr].x = fmaf(sg, hv[rr].x, px);
            hv[rr].y = fmaf(sg, hv[rr].y, py);
        }
    }
    #pragma unroll
    for (int rr = 0; rr < 8; rr++) {
        int m = wv * 8 + rr;
        int c = lane ^ m;
        float vr = hv[rr].y * sc1, vi = -hv[rr].x * sc1;
        short rh = f2bf(vr), rl = f2bf(vr - bf2f(rh));
        short ih = f2bf(vi), il = f2bf(vi - bf2f(ih));
        int off = idxSw(lane, c);
        S0[off] = rh; S0[4096 + off] = rl; S0[8192 + off] = ih; S0[12288 + off] = il;
    }
    __syncthreads();

    const float4v z4 = {0.f, 0.f, 0.f, 0.f};
    float4v accR[NT], accI[NT];
    #define ZERO_ACC _Pragma("unroll") for (int i2 = 0; i2 < NT; i2++) { accR[i2]=z4; accI[i2]=z4; }

    ZERO_ACC
    mm_mfma<0, 1, NDM, NDN>(S0, S0, li, q, mb, nb, accR, accI);
    float ss = 0.f;
    #pragma unroll
    for (int ti = 0; ti < NT; ti++)
        #pragma unroll
        for (int e = 0; e < 4; e++)
            ss += accR[ti][e]*accR[ti][e] + accI[ti][e]*accI[ti][e];
    #pragma unroll
    for (int d = 32; d >= 1; d >>= 1) ss += __shfl_xor(ss, d, 64);
    if (lane == 0) red[8 + wv] = ss;
    __syncthreads();

    rs = 0.f;
    #pragma unroll
    for (int i2 = 0; i2 < 8; i2++) rs += red[8 + i2];
    float bound = sqrtf(sqrtf(rs));
    int ds = 0; { float nn = bound; while (nn > 3.4f && ds < 12) { nn *= 0.5f; ds++; } }
    const int s = s1 + ds;
    float dsc = exp2f((float)(-ds)), dsc2 = dsc * dsc;

    float4v bre[NT], bim[NT];
    gather_tile<NDM, NDN>(S0, li, q, mb, nb, bre, bim);

    #pragma unroll
    for (int ti = 0; ti < NT; ti++) { ure[ti] = accR[ti] * dsc2; uim[ti] = accI[ti] * dsc2; }
    write_rowT<NDM, NDN>(S1, li, q, mb, nb, ure, uim);
    __syncthreads();

    {
        float ca = C15f * dsc;
        #pragma unroll
        for (int ti = 0; ti < NT; ti++) { ure[ti] = ca * bre[ti]; uim[ti] = ca * bim[ti]; }
        adddiag<NDM, NDN>(ure, C14f, li, q, mb, nb);
        write_rowT<NDM, NDN>(S0, li, q, mb, nb, ure, uim);
    }
    __syncthreads();

    const float cIc[7] = { C0f, C2f, C4f, C6f, C8f, C10f, C12f };
    const float cAc[7] = { C1f, C3f, C5f, C7f, C9f, C11f, C13f };
    for (int j = 6; j >= 0; j--) {
        ZERO_ACC
        mm_mfma<2, 0, NDM, NDN>(S1, S0, li, q, mb, nb, accR, accI);
        __syncthreads();
        float ca = cAc[j] * dsc, cI = cIc[j];
        #pragma unroll
        for (int ti = 0; ti < NT; ti++) {
            ure[ti] = accR[ti] + ca * bre[ti];
            uim[ti] = accI[ti] + ca * bim[ti];
        }
        adddiag<NDM, NDN>(ure, cI, li, q, mb, nb);
        write_rowT<NDM, NDN>(S0, li, q, mb, nb, ure, uim);
        __syncthreads();
    }

    for (int sq = 0; sq < s; sq++) {
        write_row<NDM, NDN>(S1, li, q, mb, nb, ure, uim);
        if (sq > 0) write_rowT<NDM, NDN>(S0, li, q, mb, nb, ure, uim);
        __syncthreads();
        ZERO_ACC
        mm_mfma<0, 0, NDM, NDN>(S1, S0, li, q, mb, nb, accR, accI);
        __syncthreads();
        #pragma unroll
        for (int ti = 0; ti < NT; ti++) { ure[ti] = accR[ti]; uim[ti] = accI[ti]; }
    }
    #undef ZERO_ACC
}

// ================== 16-wave NT=1 helpers ==================

template<int AM, int BM>
__device__ __forceinline__ void mm_mfma1(const short* __restrict__ As,
                                         const short* __restrict__ Bs,
                                         int li, int q, int mb, int nb,
                                         float4v* __restrict__ accR,
                                         float4v* __restrict__ accI)
{
    #pragma unroll
    for (int ks = 0; ks < 2; ks++) {
        const int ch = ks * 4 + q;
        int r = (mb << 4) + li;
        int offA = (r << 6) + (((ch + r) & 7) << 3);
        short8v arh = *(const short8v*)(As + offA);
        short8v arl = *(const short8v*)(As + 4096 + offA);
        short8v aih = *(const short8v*)(As + 8192 + offA);
        short8v ail = *(const short8v*)(As + 12288 + offA);
        short8v nih = neg8(aih), nil_ = neg8(ail);
        short8v cRh = (AM == 2) ? aih : nih;
        short8v cRl = (AM == 2) ? ail : nil_;
        short8v cIh = (AM == 2) ? nih : aih;
        short8v cIl = (AM == 2) ? nil_ : ail;

        int n = (nb << 4) + li;
        int offB = (n << 6) + (((ch + n) & 7) << 3);
        short8v brh = *(const short8v*)(Bs + offB);
        short8v brl = *(const short8v*)(Bs + 4096 + offB);
        short8v bih = *(const short8v*)(Bs + 8192 + offB);
        short8v bil = *(const short8v*)(Bs + 12288 + offB);
        if (BM == 1) { brh = neg8(brh); brl = neg8(brl); }

        accR[0] = MFMA(arh, brh, accR[0]);
        accR[0] = MFMA(arh, brl, accR[0]);
        accR[0] = MFMA(arl, brh, accR[0]);
        accR[0] = MFMA(cRh, bih, accR[0]);
        accR[0] = MFMA(cRh, bil, accR[0]);
        accR[0] = MFMA(cRl, bih, accR[0]);
        accI[0] = MFMA(arh, bih, accI[0]);
        accI[0] = MFMA(arh, bil, accI[0]);
        accI[0] = MFMA(arl, bih, accI[0]);
        accI[0] = MFMA(cIh, brh, accI[0]);
        accI[0] = MFMA(cIh, brl, accI[0]);
        accI[0] = MFMA(cIl, brh, accI[0]);
    }
}

__device__ __forceinline__ void write_rowT1(short* __restrict__ S, int li, int q,
                                            int mb, int nb,
                                            const float4v* cre, const float4v* cim)
{
    int c = (nb << 4) + li;
    int k0 = (mb << 4) + q * 4;
    int off = idxSw(c, k0);
    short4v rh, rl, ih, il;
    #pragma unroll
    for (int reg = 0; reg < 4; reg++) {
        float vr = cre[0][reg], vi = cim[0][reg];
        short h1 = f2bf(vr); rh[reg] = h1; rl[reg] = f2bf(vr - bf2f(h1));
        short h2 = f2bf(vi); ih[reg] = h2; il[reg] = f2bf(vi - bf2f(h2));
    }
    *(short4v*)(S + off) = rh;
    *(short4v*)(S + 4096 + off) = rl;
    *(short4v*)(S + 8192 + off) = ih;
    *(short4v*)(S + 12288 + off) = il;
}

// convert once; store row-major into Srow AND transposed into ST
__device__ __forceinline__ void write_both1(short* __restrict__ Srow,
                                            short* __restrict__ ST, int li, int q,
                                            int mb, int nb,
                                            const float4v* cre, const float4v* cim)
{
    int c = (nb << 4) + li;
    int k0 = (mb << 4) + q * 4;
    int offT = idxSw(c, k0);
    short4v rh4, rl4, ih4, il4;
    #pragma unroll
    for (int reg = 0; reg < 4; reg++) {
        float vr = cre[0][reg], vi = cim[0][reg];
        short rh = f2bf(vr), rl = f2bf(vr - bf2f(rh));
        short ih = f2bf(vi), il = f2bf(vi - bf2f(ih));
        rh4[reg] = rh; rl4[reg] = rl; ih4[reg] = ih; il4[reg] = il;
        int r = (mb << 4) + q * 4 + reg;
        int off = idxSw(r, c);
        Srow[off] = rh; Srow[4096 + off] = rl;
        Srow[8192 + off] = ih; Srow[12288 + off] = il;
    }
    *(short4v*)(ST + offT) = rh4;
    *(short4v*)(ST + 4096 + offT) = rl4;
    *(short4v*)(ST + 8192 + offT) = ih4;
    *(short4v*)(ST + 12288 + offT) = il4;
}

__device__ __forceinline__ void gather_tile1(const short* __restrict__ S, int li, int q,
                                             int mb, int nb, float4v* bre, float4v* bim)
{
    int c = (nb << 4) + li;
    #pragma unroll
    for (int reg = 0; reg < 4; reg++) {
        int r = (mb << 4) + q * 4 + reg;
        int off = idxSw(r, c);
        bre[0][reg] = bf2f(S[off]) + bf2f(S[4096 + off]);
        bim[0][reg] = bf2f(S[8192 + off]) + bf2f(S[12288 + off]);
    }
}

__device__ __forceinline__ void adddiag1(float4v* u, float cI, int li, int q, int mb, int nb)
{
    if (mb == nb) {
        #pragma unroll
        for (int e = 0; e < 4; e++)
            if (li == q * 4 + e) u[0][e] += cI;
    }
}

__device__ __forceinline__ void store_tiles1(cplx* __restrict__ dst, int li, int q,
                                             int mb, int nb,
                                             const float4v* ure, const float4v* uim)
{
    int c = (nb << 4) + li;
    int cs = c ^ (((c >> 4) & 1) << 1);
    #pragma unroll
    for (int reg = 0; reg < 4; reg++) {
        int r = (mb << 4) + q * 4 + reg;
        dst[(r << 6) + cs] = make_float2(ure[0][reg], uim[0][reg]);
    }
}

// ===== expm core, 16 waves NT=1, 17-phase schedule (4-quad 128KB layout) =====
// bar1 W+red | bar2 beta | bar3 mm1+red2 | bar4 V7 | Horner j=6..1 (1 bar) |
// j=0 writes U->P0 AND U^T->P3 in-phase (1 bar) | squarings 1 bar each:
// sq even reads (P0,P3) writes (P1,P2); sq odd reads (P1,P2) writes (P0,P3).
// Every write target was last read before the PREVIOUS barrier.
__device__ __forceinline__ void expm_core16(char* __restrict__ LDS,
                                            const float* __restrict__ src, bool isW,
                                            int t, float4v* ure, float4v* uim)
{
    short* P0 = (short*)LDS;
    short* P1 = (short*)(LDS + 32768);
    short* P2 = (short*)(LDS + 65536);
    short* P3 = (short*)(LDS + 98304);
    cplx*  W  = (cplx*)(LDS + 65536);       // overlays P2 (dead before V7)
    float* red = (float*)(LDS + 98304);     // overlays P3[0:128] (dead before j=6)
    const int lane = t & 63, wv = t >> 6;
    const int li = lane & 15, q = lane >> 4;
    const int mb = wv & 3, nb = wv >> 2;

    float sumsq = 0.f;
    #pragma unroll
    for (int n = 0; n < 4; n++) {
        int p = t + 1024 * n;
        int xm = 0, zm = 0;
        #pragma unroll
        for (int k = 0; k < 6; k++) {
            int d = (p >> (2 * k)) & 3;
            int hi = d >> 1, lo = d & 1;
            zm |= hi << k; xm |= (hi ^ lo) << k;
        }
        float v = isW ? ((p == 0) ? 0.f : src[p - 1])
                      : ((p < IN_DIM) ? src[p] : 0.f);
        sumsq += v * v;
        W[(xm << 6) + zm] = pauli_phase(v, xm, zm);
    }
    #pragma unroll
    for (int d = 32; d >= 1; d >>= 1) sumsq += __shfl_xor(sumsq, d, 64);
    if (lane == 0) red[wv] = sumsq;
    __syncthreads();                                    // bar1

    float rs = 0.f;
    #pragma unroll
    for (int i2 = 0; i2 < 16; i2++) rs += red[i2];
    float fro = sqrtf(64.f * rs);
    int s1 = 0; { float nn = fro; while (nn > 8.f && s1 < 24) { nn *= 0.5f; s1++; } }
    float sc1 = exp2f((float)(-s1));

    cplx hv[4];
    #pragma unroll
    for (int rr = 0; rr < 4; rr++) hv[rr] = W[((wv * 4 + rr) << 6) + lane];
    #pragma unroll
    for (int d = 1; d < 64; d <<= 1) {
        float sg = (lane & d) ? -1.f : 1.f;
        #pragma unroll
        for (int rr = 0; rr < 4; rr++) {
            float px = __shfl_xor(hv[rr].x, d, 64);
            float py = __shfl_xor(hv[rr].y, d, 64);
            hv[rr].x = fmaf(sg, hv[rr].x, px);
            hv[rr].y = fmaf(sg, hv[rr].y, py);
        }
    }
    #pragma unroll
    for (int rr = 0; rr < 4; rr++) {
        int m = wv * 4 + rr;
        int c = lane ^ m;
        float vr = hv[rr].y * sc1, vi = -hv[rr].x * sc1;
        short rh = f2bf(vr), rl = f2bf(vr - bf2f(rh));
        short ih = f2bf(vi), il = f2bf(vi - bf2f(ih));
        int off = idxSw(lane, c);
        P0[off] = rh; P0[4096 + off] = rl; P0[8192 + off] = ih; P0[12288 + off] = il;
    }
    __syncthreads();                                    // bar2

    const float4v z4 = {0.f, 0.f, 0.f, 0.f};
    float4v accR[1], accI[1];
    #define ZERO_ACC { accR[0] = z4; accI[0] = z4; }

    ZERO_ACC
    mm_mfma1<0, 1>(P0, P0, li, q, mb, nb, accR, accI);
    write_rowT1(P1, li, q, mb, nb, accR, accI);         // P1 <- B2^T (unscaled)
    float ss = 0.f;
    #pragma unroll
    for (int e = 0; e < 4; e++)
        ss += accR[0][e]*accR[0][e] + accI[0][e]*accI[0][e];
    #pragma unroll
    for (int d = 32; d >= 1; d >>= 1) ss += __shfl_xor(ss, d, 64);
    if (lane == 0) red[16 + wv] = ss;
    __syncthreads();                                    // bar3

    rs = 0.f;
    #pragma unroll
    for (int i2 = 0; i2 < 16; i2++) rs += red[16 + i2];
    float bound = sqrtf(sqrtf(rs));
    int ds = 0; { float nn = bound; while (nn > 3.4f && ds < 12) { nn *= 0.5f; ds++; } }
    const int s = s1 + ds;
    float dsc = exp2f((float)(-ds)), dsc2 = dsc * dsc;

    float4v bre[1], bim[1];
    gather_tile1(P0, li, q, mb, nb, bre, bim);

    {
        float ca = C15f * dsc;
        ure[0] = ca * bre[0]; uim[0] = ca * bim[0];
        adddiag1(ure, C14f, li, q, mb, nb);
        write_rowT1(P2, li, q, mb, nb, ure, uim);       // P2 <- V7^T
    }
    __syncthreads();                                    // bar4

    // Horner: V pings P2<->P3; A2 unscaled in P1 (dsc2 folded here).
    // j=0 writes U row->P0 and U^T->P3 in-phase (Vw==P3 at j=0).
    const float cIc[7] = { C0f, C2f, C4f, C6f, C8f, C10f, C12f };
    const float cAc[7] = { C1f, C3f, C5f, C7f, C9f, C11f, C13f };
    short* Vr = P2; short* Vw = P3;
    for (int j = 6; j >= 0; j--) {
        ZERO_ACC
        mm_mfma1<2, 0>(P1, Vr, li, q, mb, nb, accR, accI);
        float ca = cAc[j] * dsc, cI = cIc[j];
        ure[0] = dsc2 * accR[0] + ca * bre[0];
        uim[0] = dsc2 * accI[0] + ca * bim[0];
        adddiag1(ure, cI, li, q, mb, nb);
        if (j > 0) {
            write_rowT1(Vw, li, q, mb, nb, ure, uim);   // Vw last read 1 bar ago
            short* tmp = Vr; Vr = Vw; Vw = tmp;
        } else {
            write_both1(P0, P3, li, q, mb, nb, ure, uim); // P0 dead; P3==Vw
        }
        __syncthreads();
    }

    // squarings, ONE barrier each: pair ping-pong (P0,P3) <-> (P1,P2)
    for (int sq = 0; sq < s; sq++) {
        short* Ua = (sq & 1) ? P1 : P0;     // row-major U
        short* Ub = (sq & 1) ? P2 : P3;     // U^T
        ZERO_ACC
        mm_mfma1<0, 0>(Ua, Ub, li, q, mb, nb, accR, accI);
        ure[0] = accR[0]; uim[0] = accI[0];
        if (sq < s - 1)
            write_both1((sq & 1) ? P0 : P1, (sq & 1) ? P3 : P2,
                        li, q, mb, nb, ure, uim);
        __syncthreads();
    }
    #undef ZERO_ACC
}

// 8-wave matvec (R3-verbatim)
__device__ __forceinline__ cplx matvec_wave8(const cplx* __restrict__ M,
                                             const cplx* __restrict__ pin,
                                             int lane, int wv)
{
    const int ri = lane & 7;
    const int rr = (wv << 3) + ri;
    const int kc = lane >> 3;
    const int ch = (kc + ri) & 7;
    const int b  = (ch >> 1) & 1;
    const float4* Mr = (const float4*)(M + (rr << 6)) + (ch << 2);
    float4 m0 = Mr[0 ^ b], m1 = Mr[1 ^ b], m2 = Mr[2 ^ b], m3 = Mr[3 ^ b];
    const cplx* p = pin + (ch << 3);
    cplx p0 = p[0], p1 = p[1], p2 = p[2], p3 = p[3];
    cplx p4 = p[4], p5 = p[5], p6 = p[6], p7 = p[7];
    float ax = 0.f, ay = 0.f;
    ax = fmaf(m0.x, p0.x, fmaf(-m0.y, p0.y, ax));
    ay = fmaf(m0.x, p0.y, fmaf( m0.y, p0.x, ay));
    ax = fmaf(m0.z, p1.x, fmaf(-m0.w, p1.y, ax));
    ay = fmaf(m0.z, p1.y, fmaf( m0.w, p1.x, ay));
    ax = fmaf(m1.x, p2.x, fmaf(-m1.y, p2.y, ax));
    ay = fmaf(m1.x, p2.y, fmaf( m1.y, p2.x, ay));
    ax = fmaf(m1.z, p3.x, fmaf(-m1.w, p3.y, ax));
    ay = fmaf(m1.z, p3.y, fmaf( m1.w, p3.x, ay));
    ax = fmaf(m2.x, p4.x, fmaf(-m2.y, p4.y, ax));
    ay = fmaf(m2.x, p4.y, fmaf( m2.y, p4.x, ay));
    ax = fmaf(m2.z, p5.x, fmaf(-m2.w, p5.y, ax));
    ay = fmaf(m2.z, p5.y, fmaf( m2.w, p5.x, ay));
    ax = fmaf(m3.x, p6.x, fmaf(-m3.y, p6.y, ax));
    ay = fmaf(m3.x, p6.y, fmaf( m3.y, p6.x, ay));
    ax = fmaf(m3.z, p7.x, fmaf(-m3.w, p7.y, ax));
    ay = fmaf(m3.z, p7.y, fmaf( m3.w, p7.x, ay));
    ax += __shfl_xor(ax, 8, 64);  ay += __shfl_xor(ay, 8, 64);
    ax += __shfl_xor(ax, 16, 64); ay += __shfl_xor(ay, 16, 64);
    ax += __shfl_xor(ax, 32, 64); ay += __shfl_xor(ay, 32, 64);
    return make_float2(ax, ay);
}

// ===== kernel 1: Up[r] -> ws; grid 4, 16-wave 17-phase core =====
__global__ __launch_bounds__(1024) void up_kernel(const float* __restrict__ w,
                                                  cplx* __restrict__ ws)
{
    __shared__ float4 LDSf4[8192];          // 131072 B
    char* LDS = (char*)LDSf4;
    const int t = threadIdx.x, r = blockIdx.x;
    const int lane = t & 63, wv = t >> 6, li = lane & 15, q = lane >> 4;
    const int mb = wv & 3, nb = wv >> 2;
    float4v ure[1], uim[1];
    expm_core16(LDS, w + (size_t)r * 4095, true, t, ure, uim);
    store_tiles1(ws + ((size_t)r << 12), li, q, mb, nb, ure, uim);
}

// ===== kernel 2: sample expm + circuit; grid 512, 8-wave, 2 blocks/CU =====
__global__ __launch_bounds__(512, 4) void circuit_kernel(const float* __restrict__ x,
                                                         const cplx* __restrict__ ws,
                                                         const float* __restrict__ bias,
                                                         float* __restrict__ out)
{
    __shared__ float4 LDSf4[4168];          // 66688 B -> 2 blocks/CU
    char* LDS = (char*)LDSf4;
    const int t = threadIdx.x, b = blockIdx.x;
    const int lane = t & 63, wv = t >> 6, li = lane & 15, q = lane >> 4;
    const int mb = wv & 3, nb = (wv >> 2) << 1;
    float4v ure[2], uim[2];

    expm_core8(LDS, x + (size_t)b * IN_DIM, false, t, ure, uim);

    cplx* Ud   = (cplx*)(LDS + 32768);      // overwrites S1 planes (fenced)
    cplx* UpS  = (cplx*)LDS;                // overwrites S0 planes
    cplx* psiA = (cplx*)(LDS + 65664);
    cplx* psiB = (cplx*)(LDS + 66176);

    store_tiles<1, 2>(Ud, li, q, mb, nb, ure, uim);
    if (t < 64) psiA[t] = make_float2(t == 0 ? 1.f : 0.f, 0.f);
    __syncthreads();                         // fences Ud + psiA (ws ready: stream order)

    const int rowi = (wv << 3) + (lane & 7);
    for (int r = 0; r < NREPS; r++) {
        {   // stage Up[r] into S0 region (read after the mid barrier)
            const float4* srcv = (const float4*)(ws + ((size_t)r << 12));
            float4* dstY = (float4*)UpS;
            #pragma unroll
            for (int n = 0; n < 4; n++) dstY[n * 512 + t] = srcv[n * 512 + t];
        }
        cplx v1 = matvec_wave8(Ud, psiA, lane, wv);
        if (lane < 8) psiB[rowi] = v1;
        __syncthreads();                    // fences stage + psiB
        cplx v2 = matvec_wave8(UpS, psiB, lane, wv);
        if (lane < 8) psiA[rowi] = v2;
        __syncthreads();                    // fences psiA + UpS reuse
    }
    if (t < 64) {
        cplx pv = psiA[t];
        out[(b << 6) + t] = fmaf(pv.x, pv.x, fmaf(pv.y, pv.y, bias[t]));
    }
}

extern "C" void kernel_launch(void* const* d_in, const int* in_sizes, int n_in,
                              void* d_out, int out_size, void* d_ws, size_t ws_size,
                              hipStream_t stream)
{
    const float* x    = (const float*)d_in[0];
    const float* w    = (const float*)d_in[1];
    const float* bias = (const float*)d_in[2];
    float* out = (float*)d_out;
    cplx* ws   = (cplx*)d_ws;               // 4 * 32 KB Up matrices

    int B = in_sizes[0] / IN_DIM;           // 512

    hipLaunchKernelGGL(up_kernel,      dim3(NREPS), dim3(1024), 0, stream, w, ws);
    hipLaunchKernelGGL(circuit_kernel, dim3(B),     dim3(512),  0, stream, x, ws, bias, out);
}

// Round 13
// 145.838 us; speedup vs baseline: 1.2003x; 1.0013x over previous
//
#include <hip/hip_runtime.h>
#include <math.h>

typedef float2 cplx;
typedef __attribute__((ext_vector_type(8))) short short8v;
typedef __attribute__((ext_vector_type(4))) short short4v;
typedef __attribute__((ext_vector_type(4))) float float4v;

#define IN_DIM 4000
#define NREPS 4

// 1/k! 0..15
#define C0f  1.0f
#define C1f  1.0f
#define C2f  0.5f
#define C3f  0.16666667f
#define C4f  0.041666668f
#define C5f  8.3333333e-3f
#define C6f  1.3888889e-3f
#define C7f  1.9841270e-4f
#define C8f  2.4801587e-5f
#define C9f  2.7557319e-6f
#define C10f 2.7557319e-7f
#define C11f 2.5052108e-8f
#define C12f 2.0876757e-9f
#define C13f 1.6059044e-10f
#define C14f 1.1470746e-11f
#define C15f 7.6471637e-13f

#define MFMA(A,B,C) __builtin_amdgcn_mfma_f32_16x16x32_bf16((A),(B),(C),0,0,0)

// ---------------------------------------------------------------------------
// R12 (best, 146.0us) with ONE change: the MFMA sequences in mm_mfma /
// mm_mfma1 interleave the two INDEPENDENT accumulator chains (accR/accI)
// as R,I,R,I,... instead of 6xR then 6xI. Per-accumulator op order is
// UNCHANGED -> bit-identical numerics (absmax must stay 0.015625).
// Theory: MFMA dependent-issue latency ~16-32cyc; in-order issue means each
// accR op stalls on its predecessor while the independent accI chain waits
// behind it. Interleaving halves the per-mm dependent chain (~24 -> ~12
// stalls), x14 mm phases in the expm. MfmaUtil 25% (chain-limited, not
// throughput-limited) is the matching symptom.
// Everything else R12-verbatim: two-kernel build, up = 16-wave 17-phase,
// circuit = 8-wave 2-blk/CU + 4-rep matvec circuit.
// ---------------------------------------------------------------------------

__device__ __forceinline__ int idxSw(int a, int b) {
    return (a << 6) + ((((b >> 3) + a) & 7) << 3) + (b & 7);
}
__device__ __forceinline__ short f2bf(float f) {   // RNE to bf16
    unsigned u = __float_as_uint(f);
    return (short)((u + 0x7FFF + ((u >> 16) & 1)) >> 16);
}
__device__ __forceinline__ float bf2f(short s) {
    return __uint_as_float(((unsigned)(unsigned short)s) << 16);
}
__device__ __forceinline__ short8v neg8(short8v a) {
    int4 u; __builtin_memcpy(&u, &a, 16);
    u.x ^= 0x80008000; u.y ^= 0x80008000; u.z ^= 0x80008000; u.w ^= 0x80008000;
    short8v r; __builtin_memcpy(&r, &u, 16); return r;
}

__device__ __forceinline__ cplx pauli_phase(float v, int xm, int zm) {
    int ny = __popc(xm & zm) & 3;
    if (ny == 0) return make_float2(v, 0.f);
    if (ny == 1) return make_float2(0.f, -v);
    if (ny == 2) return make_float2(-v, 0.f);
    return make_float2(0.f, v);
}

// ======================= 8-wave helpers =======================

// C = L*R. AM=2: storage holds conj(L). BM=1: storage rows are -R^T re.
// MFMA order: R/I chains interleaved (independent accumulators).
template<int AM, int BM, int NDM, int NDN>
__device__ __forceinline__ void mm_mfma(const short* __restrict__ As,
                                        const short* __restrict__ Bs,
                                        int li, int q, int mb, int nb,
                                        float4v* __restrict__ accR,
                                        float4v* __restrict__ accI)
{
    #pragma unroll
    for (int ks = 0; ks < 2; ks++) {
        const int ch = ks * 4 + q;
        short8v arh[NDM], arl[NDM], cRh[NDM], cRl[NDM], cIh[NDM], cIl[NDM];
        #pragma unroll
        for (int dm = 0; dm < NDM; dm++) {
            int r = ((mb + dm) << 4) + li;
            int off = (r << 6) + (((ch + r) & 7) << 3);
            arh[dm] = *(const short8v*)(As + off);
            arl[dm] = *(const short8v*)(As + 4096 + off);
            short8v aih = *(const short8v*)(As + 8192 + off);
            short8v ail = *(const short8v*)(As + 12288 + off);
            short8v nih = neg8(aih), nil_ = neg8(ail);
            cRh[dm] = (AM == 2) ? aih : nih;
            cRl[dm] = (AM == 2) ? ail : nil_;
            cIh[dm] = (AM == 2) ? nih : aih;
            cIl[dm] = (AM == 2) ? nil_ : ail;
        }
        #pragma unroll
        for (int dn = 0; dn < NDN; dn++) {
            int n = ((nb + dn) << 4) + li;
            int off = (n << 6) + (((ch + n) & 7) << 3);
            short8v brh = *(const short8v*)(Bs + off);
            short8v brl = *(const short8v*)(Bs + 4096 + off);
            short8v bih = *(const short8v*)(Bs + 8192 + off);
            short8v bil = *(const short8v*)(Bs + 12288 + off);
            if (BM == 1) { brh = neg8(brh); brl = neg8(brl); }
            __builtin_amdgcn_s_setprio(1);
            #pragma unroll
            for (int dm = 0; dm < NDM; dm++) {
                int ti = dm * NDN + dn;
                accR[ti] = MFMA(arh[dm], brh, accR[ti]);
                accI[ti] = MFMA(arh[dm], bih, accI[ti]);
                accR[ti] = MFMA(arh[dm], brl, accR[ti]);
                accI[ti] = MFMA(arh[dm], bil, accI[ti]);
                accR[ti] = MFMA(arl[dm], brh, accR[ti]);
                accI[ti] = MFMA(arl[dm], bih, accI[ti]);
                accR[ti] = MFMA(cRh[dm], bih, accR[ti]);
                accI[ti] = MFMA(cIh[dm], brh, accI[ti]);
                accR[ti] = MFMA(cRh[dm], bil, accR[ti]);
                accI[ti] = MFMA(cIh[dm], brl, accI[ti]);
                accR[ti] = MFMA(cRl[dm], bih, accR[ti]);
                accI[ti] = MFMA(cIl[dm], brh, accI[ti]);
            }
            __builtin_amdgcn_s_setprio(0);
        }
    }
}

template<int NDM, int NDN>
__device__ __forceinline__ void write_row(short* __restrict__ S, int li, int q,
                                          int mb, int nb,
                                          const float4v* cre, const float4v* cim)
{
    #pragma unroll
    for (int dm = 0; dm < NDM; dm++)
    #pragma unroll
    for (int dn = 0; dn < NDN; dn++) {
        int ti = dm * NDN + dn;
        int c = ((nb + dn) << 4) + li;
        #pragma unroll
        for (int reg = 0; reg < 4; reg++) {
            int r = ((mb + dm) << 4) + q * 4 + reg;
            int off = idxSw(r, c);
            float vr = cre[ti][reg], vi = cim[ti][reg];
            short rh = f2bf(vr), rl = f2bf(vr - bf2f(rh));
            short ih = f2bf(vi), il = f2bf(vi - bf2f(ih));
            S[off] = rh; S[4096 + off] = rl; S[8192 + off] = ih; S[12288 + off] = il;
        }
    }
}

template<int NDM, int NDN>
__device__ __forceinline__ void write_rowT(short* __restrict__ S, int li, int q,
                                           int mb, int nb,
                                           const float4v* cre, const float4v* cim)
{
    #pragma unroll
    for (int dm = 0; dm < NDM; dm++)
    #pragma unroll
    for (int dn = 0; dn < NDN; dn++) {
        int ti = dm * NDN + dn;
        int c = ((nb + dn) << 4) + li;
        int k0 = ((mb + dm) << 4) + q * 4;
        int off = idxSw(c, k0);
        short4v rh, rl, ih, il;
        #pragma unroll
        for (int reg = 0; reg < 4; reg++) {
            float vr = cre[ti][reg], vi = cim[ti][reg];
            short h1 = f2bf(vr); rh[reg] = h1; rl[reg] = f2bf(vr - bf2f(h1));
            short h2 = f2bf(vi); ih[reg] = h2; il[reg] = f2bf(vi - bf2f(h2));
        }
        *(short4v*)(S + off) = rh;
        *(short4v*)(S + 4096 + off) = rl;
        *(short4v*)(S + 8192 + off) = ih;
        *(short4v*)(S + 12288 + off) = il;
    }
}

template<int NDM, int NDN>
__device__ __forceinline__ void gather_tile(const short* __restrict__ S, int li, int q,
                                            int mb, int nb, float4v* bre, float4v* bim)
{
    #pragma unroll
    for (int dm = 0; dm < NDM; dm++)
    #pragma unroll
    for (int dn = 0; dn < NDN; dn++) {
        int ti = dm * NDN + dn;
        int c = ((nb + dn) << 4) + li;
        #pragma unroll
        for (int reg = 0; reg < 4; reg++) {
            int r = ((mb + dm) << 4) + q * 4 + reg;
            int off = idxSw(r, c);
            bre[ti][reg] = bf2f(S[off]) + bf2f(S[4096 + off]);
            bim[ti][reg] = bf2f(S[8192 + off]) + bf2f(S[12288 + off]);
        }
    }
}

template<int NDM, int NDN>
__device__ __forceinline__ void adddiag(float4v* u, float cI, int li, int q, int mb, int nb)
{
    #pragma unroll
    for (int dm = 0; dm < NDM; dm++)
    #pragma unroll
    for (int dn = 0; dn < NDN; dn++) {
        if (mb + dm == nb + dn) {
            #pragma unroll
            for (int e = 0; e < 4; e++)
                if (li == q * 4 + e) u[dm * NDN + dn][e] += cI;
        }
    }
}

template<int NDM, int NDN>
__device__ __forceinline__ void store_tiles(cplx* __restrict__ dst, int li, int q,
                                            int mb, int nb,
                                            const float4v* ure, const float4v* uim)
{
    #pragma unroll
    for (int dm = 0; dm < NDM; dm++)
    #pragma unroll
    for (int dn = 0; dn < NDN; dn++) {
        int ti = dm * NDN + dn;
        int c = ((nb + dn) << 4) + li;
        int cs = c ^ (((c >> 4) & 1) << 1);
        #pragma unroll
        for (int reg = 0; reg < 4; reg++) {
            int r = ((mb + dm) << 4) + q * 4 + reg;
            dst[(r << 6) + cs] = make_float2(ure[ti][reg], uim[ti][reg]);
        }
    }
}

// ===== expm core, 8 waves (2-quad S0/S1 layout, 67KB LDS) =====
__device__ __forceinline__ void expm_core8(char* __restrict__ LDS,
                                           const float* __restrict__ src, bool isW,
                                           int t, float4v* ure, float4v* uim)
{
    constexpr int NDM = 1, NDN = 2, NT = 2;
    short* S0 = (short*)LDS;
    short* S1 = (short*)(LDS + 32768);
    cplx*  W  = (cplx*)(LDS + 32768);
    float* red = (float*)(LDS + 65536);
    const int lane = t & 63, wv = t >> 6;
    const int li = lane & 15, q = lane >> 4;
    const int mb = wv & 3, nb = (wv >> 2) << 1;

    float sumsq = 0.f;
    #pragma unroll
    for (int n = 0; n < 8; n++) {
        int p = t + 512 * n;
        int xm = 0, zm = 0;
        #pragma unroll
        for (int k = 0; k < 6; k++) {
            int d = (p >> (2 * k)) & 3;
            int hi = d >> 1, lo = d & 1;
            zm |= hi << k; xm |= (hi ^ lo) << k;
        }
        float v = isW ? ((p == 0) ? 0.f : src[p - 1])
                      : ((p < IN_DIM) ? src[p] : 0.f);
        sumsq += v * v;
        W[(xm << 6) + zm] = pauli_phase(v, xm, zm);
    }
    #pragma unroll
    for (int d = 32; d >= 1; d >>= 1) sumsq += __shfl_xor(sumsq, d, 64);
    if (lane == 0) red[wv] = sumsq;
    __syncthreads();

    float rs = 0.f;
    #pragma unroll
    for (int i2 = 0; i2 < 8; i2++) rs += red[i2];
    float fro = sqrtf(64.f * rs);
    int s1 = 0; { float nn = fro; while (nn > 8.f && s1 < 24) { nn *= 0.5f; s1++; } }
    float sc1 = exp2f((float)(-s1));

    cplx hv[8];
    #pragma unroll
    for (int rr = 0; rr < 8; rr++) hv[rr] = W[((wv * 8 + rr) << 6) + lane];
    #pragma unroll
    for (int d = 1; d < 64; d <<= 1) {
        float sg = (lane & d) ? -1.f : 1.f;
        #pragma unroll
        for (int rr = 0; rr < 8; rr++) {
            float px = __shfl_xor(hv[rr].x, d, 64);
            float py = __shfl_xor(hv[rr].y, d, 64);
            hv[rr].x = fmaf(sg, hv[rr].x, px);
            hv[rr].y = fmaf(sg, hv[rr].y, py);
        }
    }
    #pragma unroll
    for (int rr = 0; rr < 8; rr++) {
        int m = wv * 8 + rr;
        int c = lane ^ m;
        float vr = hv[rr].y * sc1, vi = -hv[rr].x * sc1;
        short rh = f2bf(vr), rl = f2bf(vr - bf2f(rh));
        short ih = f2bf(vi), il = f2bf(vi - bf2f(ih));
        int off = idxSw(lane, c);
        S0[off] = rh; S0[4096 + off] = rl; S0[8192 + off] = ih; S0[12288 + off] = il;
    }
    __syncthreads();

    const float4v z4 = {0.f, 0.f, 0.f, 0.f};
    float4v accR[NT], accI[NT];
    #define ZERO_ACC _Pragma("unroll") for (int i2 = 0; i2 < NT; i2++) { accR[i2]=z4; accI[i2]=z4; }

    ZERO_ACC
    mm_mfma<0, 1, NDM, NDN>(S0, S0, li, q, mb, nb, accR, accI);
    float ss = 0.f;
    #pragma unroll
    for (int ti = 0; ti < NT; ti++)
        #pragma unroll
        for (int e = 0; e < 4; e++)
            ss += accR[ti][e]*accR[ti][e] + accI[ti][e]*accI[ti][e];
    #pragma unroll
    for (int d = 32; d >= 1; d >>= 1) ss += __shfl_xor(ss, d, 64);
    if (lane == 0) red[8 + wv] = ss;
    __syncthreads();

    rs = 0.f;
    #pragma unroll
    for (int i2 = 0; i2 < 8; i2++) rs += red[8 + i2];
    float bound = sqrtf(sqrtf(rs));
    int ds = 0; { float nn = bound; while (nn > 3.4f && ds < 12) { nn *= 0.5f; ds++; } }
    const int s = s1 + ds;
    float dsc = exp2f((float)(-ds)), dsc2 = dsc * dsc;

    float4v bre[NT], bim[NT];
    gather_tile<NDM, NDN>(S0, li, q, mb, nb, bre, bim);

    #pragma unroll
    for (int ti = 0; ti < NT; ti++) { ure[ti] = accR[ti] * dsc2; uim[ti] = accI[ti] * dsc2; }
    write_rowT<NDM, NDN>(S1, li, q, mb, nb, ure, uim);
    __syncthreads();

    {
        float ca = C15f * dsc;
        #pragma unroll
        for (int ti = 0; ti < NT; ti++) { ure[ti] = ca * bre[ti]; uim[ti] = ca * bim[ti]; }
        adddiag<NDM, NDN>(ure, C14f, li, q, mb, nb);
        write_rowT<NDM, NDN>(S0, li, q, mb, nb, ure, uim);
    }
    __syncthreads();

    const float cIc[7] = { C0f, C2f, C4f, C6f, C8f, C10f, C12f };
    const float cAc[7] = { C1f, C3f, C5f, C7f, C9f, C11f, C13f };
    for (int j = 6; j >= 0; j--) {
        ZERO_ACC
        mm_mfma<2, 0, NDM, NDN>(S1, S0, li, q, mb, nb, accR, accI);
        __syncthreads();
        float ca = cAc[j] * dsc, cI = cIc[j];
        #pragma unroll
        for (int ti = 0; ti < NT; ti++) {
            ure[ti] = accR[ti] + ca * bre[ti];
            uim[ti] = accI[ti] + ca * bim[ti];
        }
        adddiag<NDM, NDN>(ure, cI, li, q, mb, nb);
        write_rowT<NDM, NDN>(S0, li, q, mb, nb, ure, uim);
        __syncthreads();
    }

    for (int sq = 0; sq < s; sq++) {
        write_row<NDM, NDN>(S1, li, q, mb, nb, ure, uim);
        if (sq > 0) write_rowT<NDM, NDN>(S0, li, q, mb, nb, ure, uim);
        __syncthreads();
        ZERO_ACC
        mm_mfma<0, 0, NDM, NDN>(S1, S0, li, q, mb, nb, accR, accI);
        __syncthreads();
        #pragma unroll
        for (int ti = 0; ti < NT; ti++) { ure[ti] = accR[ti]; uim[ti] = accI[ti]; }
    }
    #undef ZERO_ACC
}

// ================== 16-wave NT=1 helpers ==================

template<int AM, int BM>
__device__ __forceinline__ void mm_mfma1(const short* __restrict__ As,
                                         const short* __restrict__ Bs,
                                         int li, int q, int mb, int nb,
                                         float4v* __restrict__ accR,
                                         float4v* __restrict__ accI)
{
    #pragma unroll
    for (int ks = 0; ks < 2; ks++) {
        const int ch = ks * 4 + q;
        int r = (mb << 4) + li;
        int offA = (r << 6) + (((ch + r) & 7) << 3);
        short8v arh = *(const short8v*)(As + offA);
        short8v arl = *(const short8v*)(As + 4096 + offA);
        short8v aih = *(const short8v*)(As + 8192 + offA);
        short8v ail = *(const short8v*)(As + 12288 + offA);
        short8v nih = neg8(aih), nil_ = neg8(ail);
        short8v cRh = (AM == 2) ? aih : nih;
        short8v cRl = (AM == 2) ? ail : nil_;
        short8v cIh = (AM == 2) ? nih : aih;
        short8v cIl = (AM == 2) ? nil_ : ail;

        int n = (nb << 4) + li;
        int offB = (n << 6) + (((ch + n) & 7) << 3);
        short8v brh = *(const short8v*)(Bs + offB);
        short8v brl = *(const short8v*)(Bs + 4096 + offB);
        short8v bih = *(const short8v*)(Bs + 8192 + offB);
        short8v bil = *(const short8v*)(Bs + 12288 + offB);
        if (BM == 1) { brh = neg8(brh); brl = neg8(brl); }

        accR[0] = MFMA(arh, brh, accR[0]);
        accI[0] = MFMA(arh, bih, accI[0]);
        accR[0] = MFMA(arh, brl, accR[0]);
        accI[0] = MFMA(arh, bil, accI[0]);
        accR[0] = MFMA(arl, brh, accR[0]);
        accI[0] = MFMA(arl, bih, accI[0]);
        accR[0] = MFMA(cRh, bih, accR[0]);
        accI[0] = MFMA(cIh, brh, accI[0]);
        accR[0] = MFMA(cRh, bil, accR[0]);
        accI[0] = MFMA(cIh, brl, accI[0]);
        accR[0] = MFMA(cRl, bih, accR[0]);
        accI[0] = MFMA(cIl, brh, accI[0]);
    }
}

__device__ __forceinline__ void write_rowT1(short* __restrict__ S, int li, int q,
                                            int mb, int nb,
                                            const float4v* cre, const float4v* cim)
{
    int c = (nb << 4) + li;
    int k0 = (mb << 4) + q * 4;
    int off = idxSw(c, k0);
    short4v rh, rl, ih, il;
    #pragma unroll
    for (int reg = 0; reg < 4; reg++) {
        float vr = cre[0][reg], vi = cim[0][reg];
        short h1 = f2bf(vr); rh[reg] = h1; rl[reg] = f2bf(vr - bf2f(h1));
        short h2 = f2bf(vi); ih[reg] = h2; il[reg] = f2bf(vi - bf2f(h2));
    }
    *(short4v*)(S + off) = rh;
    *(short4v*)(S + 4096 + off) = rl;
    *(short4v*)(S + 8192 + off) = ih;
    *(short4v*)(S + 12288 + off) = il;
}

// convert once; store row-major into Srow AND transposed into ST
__device__ __forceinline__ void write_both1(short* __restrict__ Srow,
                                            short* __restrict__ ST, int li, int q,
                                            int mb, int nb,
                                            const float4v* cre, const float4v* cim)
{
    int c = (nb << 4) + li;
    int k0 = (mb << 4) + q * 4;
    int offT = idxSw(c, k0);
    short4v rh4, rl4, ih4, il4;
    #pragma unroll
    for (int reg = 0; reg < 4; reg++) {
        float vr = cre[0][reg], vi = cim[0][reg];
        short rh = f2bf(vr), rl = f2bf(vr - bf2f(rh));
        short ih = f2bf(vi), il = f2bf(vi - bf2f(ih));
        rh4[reg] = rh; rl4[reg] = rl; ih4[reg] = ih; il4[reg] = il;
        int r = (mb << 4) + q * 4 + reg;
        int off = idxSw(r, c);
        Srow[off] = rh; Srow[4096 + off] = rl;
        Srow[8192 + off] = ih; Srow[12288 + off] = il;
    }
    *(short4v*)(ST + offT) = rh4;
    *(short4v*)(ST + 4096 + offT) = rl4;
    *(short4v*)(ST + 8192 + offT) = ih4;
    *(short4v*)(ST + 12288 + offT) = il4;
}

__device__ __forceinline__ void gather_tile1(const short* __restrict__ S, int li, int q,
                                             int mb, int nb, float4v* bre, float4v* bim)
{
    int c = (nb << 4) + li;
    #pragma unroll
    for (int reg = 0; reg < 4; reg++) {
        int r = (mb << 4) + q * 4 + reg;
        int off = idxSw(r, c);
        bre[0][reg] = bf2f(S[off]) + bf2f(S[4096 + off]);
        bim[0][reg] = bf2f(S[8192 + off]) + bf2f(S[12288 + off]);
    }
}

__device__ __forceinline__ void adddiag1(float4v* u, float cI, int li, int q, int mb, int nb)
{
    if (mb == nb) {
        #pragma unroll
        for (int e = 0; e < 4; e++)
            if (li == q * 4 + e) u[0][e] += cI;
    }
}

__device__ __forceinline__ void store_tiles1(cplx* __restrict__ dst, int li, int q,
                                             int mb, int nb,
                                             const float4v* ure, const float4v* uim)
{
    int c = (nb << 4) + li;
    int cs = c ^ (((c >> 4) & 1) << 1);
    #pragma unroll
    for (int reg = 0; reg < 4; reg++) {
        int r = (mb << 4) + q * 4 + reg;
        dst[(r << 6) + cs] = make_float2(ure[0][reg], uim[0][reg]);
    }
}

// ===== expm core, 16 waves NT=1, 17-phase schedule (4-quad 128KB layout) =====
__device__ __forceinline__ void expm_core16(char* __restrict__ LDS,
                                            const float* __restrict__ src, bool isW,
                                            int t, float4v* ure, float4v* uim)
{
    short* P0 = (short*)LDS;
    short* P1 = (short*)(LDS + 32768);
    short* P2 = (short*)(LDS + 65536);
    short* P3 = (short*)(LDS + 98304);
    cplx*  W  = (cplx*)(LDS + 65536);       // overlays P2 (dead before V7)
    float* red = (float*)(LDS + 98304);     // overlays P3[0:128] (dead before j=6)
    const int lane = t & 63, wv = t >> 6;
    const int li = lane & 15, q = lane >> 4;
    const int mb = wv & 3, nb = wv >> 2;

    float sumsq = 0.f;
    #pragma unroll
    for (int n = 0; n < 4; n++) {
        int p = t + 1024 * n;
        int xm = 0, zm = 0;
        #pragma unroll
        for (int k = 0; k < 6; k++) {
            int d = (p >> (2 * k)) & 3;
            int hi = d >> 1, lo = d & 1;
            zm |= hi << k; xm |= (hi ^ lo) << k;
        }
        float v = isW ? ((p == 0) ? 0.f : src[p - 1])
                      : ((p < IN_DIM) ? src[p] : 0.f);
        sumsq += v * v;
        W[(xm << 6) + zm] = pauli_phase(v, xm, zm);
    }
    #pragma unroll
    for (int d = 32; d >= 1; d >>= 1) sumsq += __shfl_xor(sumsq, d, 64);
    if (lane == 0) red[wv] = sumsq;
    __syncthreads();                                    // bar1

    float rs = 0.f;
    #pragma unroll
    for (int i2 = 0; i2 < 16; i2++) rs += red[i2];
    float fro = sqrtf(64.f * rs);
    int s1 = 0; { float nn = fro; while (nn > 8.f && s1 < 24) { nn *= 0.5f; s1++; } }
    float sc1 = exp2f((float)(-s1));

    cplx hv[4];
    #pragma unroll
    for (int rr = 0; rr < 4; rr++) hv[rr] = W[((wv * 4 + rr) << 6) + lane];
    #pragma unroll
    for (int d = 1; d < 64; d <<= 1) {
        float sg = (lane & d) ? -1.f : 1.f;
        #pragma unroll
        for (int rr = 0; rr < 4; rr++) {
            float px = __shfl_xor(hv[rr].x, d, 64);
            float py = __shfl_xor(hv[rr].y, d, 64);
            hv[rr].x = fmaf(sg, hv[rr].x, px);
            hv[rr].y = fmaf(sg, hv[rr].y, py);
        }
    }
    #pragma unroll
    for (int rr = 0; rr < 4; rr++) {
        int m = wv * 4 + rr;
        int c = lane ^ m;
        float vr = hv[rr].y * sc1, vi = -hv[rr].x * sc1;
        short rh = f2bf(vr), rl = f2bf(vr - bf2f(rh));
        short ih = f2bf(vi), il = f2bf(vi - bf2f(ih));
        int off = idxSw(lane, c);
        P0[off] = rh; P0[4096 + off] = rl; P0[8192 + off] = ih; P0[12288 + off] = il;
    }
    __syncthreads();                                    // bar2

    const float4v z4 = {0.f, 0.f, 0.f, 0.f};
    float4v accR[1], accI[1];
    #define ZERO_ACC { accR[0] = z4; accI[0] = z4; }

    ZERO_ACC
    mm_mfma1<0, 1>(P0, P0, li, q, mb, nb, accR, accI);
    write_rowT1(P1, li, q, mb, nb, accR, accI);         // P1 <- B2^T (unscaled)
    float ss = 0.f;
    #pragma unroll
    for (int e = 0; e < 4; e++)
        ss += accR[0][e]*accR[0][e] + accI[0][e]*accI[0][e];
    #pragma unroll
    for (int d = 32; d >= 1; d >>= 1) ss += __shfl_xor(ss, d, 64);
    if (lane == 0) red[16 + wv] = ss;
    __syncthreads();                                    // bar3

    rs = 0.f;
    #pragma unroll
    for (int i2 = 0; i2 < 16; i2++) rs += red[16 + i2];
    float bound = sqrtf(sqrtf(rs));
    int ds = 0; { float nn = bound; while (nn > 3.4f && ds < 12) { nn *= 0.5f; ds++; } }
    const int s = s1 + ds;
    float dsc = exp2f((float)(-ds)), dsc2 = dsc * dsc;

    float4v bre[1], bim[1];
    gather_tile1(P0, li, q, mb, nb, bre, bim);

    {
        float ca = C15f * dsc;
        ure[0] = ca * bre[0]; uim[0] = ca * bim[0];
        adddiag1(ure, C14f, li, q, mb, nb);
        write_rowT1(P2, li, q, mb, nb, ure, uim);       // P2 <- V7^T
    }
    __syncthreads();                                    // bar4

    const float cIc[7] = { C0f, C2f, C4f, C6f, C8f, C10f, C12f };
    const float cAc[7] = { C1f, C3f, C5f, C7f, C9f, C11f, C13f };
    short* Vr = P2; short* Vw = P3;
    for (int j = 6; j >= 0; j--) {
        ZERO_ACC
        mm_mfma1<2, 0>(P1, Vr, li, q, mb, nb, accR, accI);
        float ca = cAc[j] * dsc, cI = cIc[j];
        ure[0] = dsc2 * accR[0] + ca * bre[0];
        uim[0] = dsc2 * accI[0] + ca * bim[0];
        adddiag1(ure, cI, li, q, mb, nb);
        if (j > 0) {
            write_rowT1(Vw, li, q, mb, nb, ure, uim);   // Vw last read 1 bar ago
            short* tmp = Vr; Vr = Vw; Vw = tmp;
        } else {
            write_both1(P0, P3, li, q, mb, nb, ure, uim); // P0 dead; P3==Vw
        }
        __syncthreads();
    }

    for (int sq = 0; sq < s; sq++) {
        short* Ua = (sq & 1) ? P1 : P0;     // row-major U
        short* Ub = (sq & 1) ? P2 : P3;     // U^T
        ZERO_ACC
        mm_mfma1<0, 0>(Ua, Ub, li, q, mb, nb, accR, accI);
        ure[0] = accR[0]; uim[0] = accI[0];
        if (sq < s - 1)
            write_both1((sq & 1) ? P0 : P1, (sq & 1) ? P3 : P2,
                        li, q, mb, nb, ure, uim);
        __syncthreads();
    }
    #undef ZERO_ACC
}

// 8-wave matvec (R3-verbatim)
__device__ __forceinline__ cplx matvec_wave8(const cplx* __restrict__ M,
                                             const cplx* __restrict__ pin,
                                             int lane, int wv)
{
    const int ri = lane & 7;
    const int rr = (wv << 3) + ri;
    const int kc = lane >> 3;
    const int ch = (kc + ri) & 7;
    const int b  = (ch >> 1) & 1;
    const float4* Mr = (const float4*)(M + (rr << 6)) + (ch << 2);
    float4 m0 = Mr[0 ^ b], m1 = Mr[1 ^ b], m2 = Mr[2 ^ b], m3 = Mr[3 ^ b];
    const cplx* p = pin + (ch << 3);
    cplx p0 = p[0], p1 = p[1], p2 = p[2], p3 = p[3];
    cplx p4 = p[4], p5 = p[5], p6 = p[6], p7 = p[7];
    float ax = 0.f, ay = 0.f;
    ax = fmaf(m0.x, p0.x, fmaf(-m0.y, p0.y, ax));
    ay = fmaf(m0.x, p0.y, fmaf( m0.y, p0.x, ay));
    ax = fmaf(m0.z, p1.x, fmaf(-m0.w, p1.y, ax));
    ay = fmaf(m0.z, p1.y, fmaf( m0.w, p1.x, ay));
    ax = fmaf(m1.x, p2.x, fmaf(-m1.y, p2.y, ax));
    ay = fmaf(m1.x, p2.y, fmaf( m1.y, p2.x, ay));
    ax = fmaf(m1.z, p3.x, fmaf(-m1.w, p3.y, ax));
    ay = fmaf(m1.z, p3.y, fmaf( m1.w, p3.x, ay));
    ax = fmaf(m2.x, p4.x, fmaf(-m2.y, p4.y, ax));
    ay = fmaf(m2.x, p4.y, fmaf( m2.y, p4.x, ay));
    ax = fmaf(m2.z, p5.x, fmaf(-m2.w, p5.y, ax));
    ay = fmaf(m2.z, p5.y, fmaf( m2.w, p5.x, ay));
    ax = fmaf(m3.x, p6.x, fmaf(-m3.y, p6.y, ax));
    ay = fmaf(m3.x, p6.y, fmaf( m3.y, p6.x, ay));
    ax = fmaf(m3.z, p7.x, fmaf(-m3.w, p7.y, ax));
    ay = fmaf(m3.z, p7.y, fmaf( m3.w, p7.x, ay));
    ax += __shfl_xor(ax, 8, 64);  ay += __shfl_xor(ay, 8, 64);
    ax += __shfl_xor(ax, 16, 64); ay += __shfl_xor(ay, 16, 64);
    ax += __shfl_xor(ax, 32, 64); ay += __shfl_xor(ay, 32, 64);
    return make_float2(ax, ay);
}

// ===== kernel 1: Up[r] -> ws; grid 4, 16-wave 17-phase core =====
__global__ __launch_bounds__(1024) void up_kernel(const float* __restrict__ w,
                                                  cplx* __restrict__ ws)
{
    __shared__ float4 LDSf4[8192];          // 131072 B
    char* LDS = (char*)LDSf4;
    const int t = threadIdx.x, r = blockIdx.x;
    const int lane = t & 63, wv = t >> 6, li = lane & 15, q = lane >> 4;
    const int mb = wv & 3, nb = wv >> 2;
    float4v ure[1], uim[1];
    expm_core16(LDS, w + (size_t)r * 4095, true, t, ure, uim);
    store_tiles1(ws + ((size_t)r << 12), li, q, mb, nb, ure, uim);
}

// ===== kernel 2: sample expm + circuit; grid 512, 8-wave, 2 blocks/CU =====
__global__ __launch_bounds__(512, 4) void circuit_kernel(const float* __restrict__ x,
                                                         const cplx* __restrict__ ws,
                                                         const float* __restrict__ bias,
                                                         float* __restrict__ out)
{
    __shared__ float4 LDSf4[4168];          // 66688 B -> 2 blocks/CU
    char* LDS = (char*)LDSf4;
    const int t = threadIdx.x, b = blockIdx.x;
    const int lane = t & 63, wv = t >> 6, li = lane & 15, q = lane >> 4;
    const int mb = wv & 3, nb = (wv >> 2) << 1;
    float4v ure[2], uim[2];

    expm_core8(LDS, x + (size_t)b * IN_DIM, false, t, ure, uim);

    cplx* Ud   = (cplx*)(LDS + 32768);      // overwrites S1 planes (fenced)
    cplx* UpS  = (cplx*)LDS;                // overwrites S0 planes
    cplx* psiA = (cplx*)(LDS + 65664);
    cplx* psiB = (cplx*)(LDS + 66176);

    store_tiles<1, 2>(Ud, li, q, mb, nb, ure, uim);
    if (t < 64) psiA[t] = make_float2(t == 0 ? 1.f : 0.f, 0.f);
    __syncthreads();                         // fences Ud + psiA (ws ready: stream order)

    const int rowi = (wv << 3) + (lane & 7);
    for (int r = 0; r < NREPS; r++) {
        {   // stage Up[r] into S0 region (read after the mid barrier)
            const float4* srcv = (const float4*)(ws + ((size_t)r << 12));
            float4* dstY = (float4*)UpS;
            #pragma unroll
            for (int n = 0; n < 4; n++) dstY[n * 512 + t] = srcv[n * 512 + t];
        }
        cplx v1 = matvec_wave8(Ud, psiA, lane, wv);
        if (lane < 8) psiB[rowi] = v1;
        __syncthreads();                    // fences stage + psiB
        cplx v2 = matvec_wave8(UpS, psiB, lane, wv);
        if (lane < 8) psiA[rowi] = v2;
        __syncthreads();                    // fences psiA + UpS reuse
    }
    if (t < 64) {
        cplx pv = psiA[t];
        out[(b << 6) + t] = fmaf(pv.x, pv.x, fmaf(pv.y, pv.y, bias[t]));
    }
}

extern "C" void kernel_launch(void* const* d_in, const int* in_sizes, int n_in,
                              void* d_out, int out_size, void* d_ws, size_t ws_size,
                              hipStream_t stream)
{
    const float* x    = (const float*)d_in[0];
    const float* w    = (const float*)d_in[1];
    const float* bias = (const float*)d_in[2];
    float* out = (float*)d_out;
    cplx* ws   = (cplx*)d_ws;               // 4 * 32 KB Up matrices

    int B = in_sizes[0] / IN_DIM;           // 512

    hipLaunchKernelGGL(up_kernel,      dim3(NREPS), dim3(1024), 0, stream, w, ws);
    hipLaunchKernelGGL(circuit_kernel, dim3(B),     dim3(512),  0, stream, x, ws, bias, out);
}